// Round 1
// baseline (231.068 us; speedup 1.0000x reference)
//
#include <hip/hip_runtime.h>

#define HID 32
#define MIN_WEIGHT -100000.0f

// ---------------------------------------------------------------------------
// Fill output with MIN_WEIGHT (harness poisons d_out; we must write all 2*E).
__global__ __launch_bounds__(256) void fill_kernel(float* __restrict__ out, int n, float val) {
    int i = blockIdx.x * blockDim.x + threadIdx.x;
    int stride = gridDim.x * blockDim.x;
    for (; i < n; i += stride) out[i] = val;
}

// ---------------------------------------------------------------------------
// g = relu(row[0:IN] @ W[IN][32]) ; one thread does a whole node row.
// W accesses are wave-uniform -> compiler emits scalar (SMEM) loads.
template <int IN>
__device__ __forceinline__ void mlp_layer(const float* __restrict__ row,
                                          const float* __restrict__ W,
                                          float* __restrict__ g) {
    float acc[HID];
#pragma unroll
    for (int k = 0; k < HID; ++k) acc[k] = 0.f;
#pragma unroll 1
    for (int j0 = 0; j0 < IN; j0 += 16) {
        float4 e0 = *(const float4*)(row + j0 + 0);
        float4 e1 = *(const float4*)(row + j0 + 4);
        float4 e2 = *(const float4*)(row + j0 + 8);
        float4 e3 = *(const float4*)(row + j0 + 12);
        float ebuf[16] = {e0.x, e0.y, e0.z, e0.w, e1.x, e1.y, e1.z, e1.w,
                          e2.x, e2.y, e2.z, e2.w, e3.x, e3.y, e3.z, e3.w};
#pragma unroll
        for (int jj = 0; jj < 16; ++jj) {
            float ev = ebuf[jj];
            const float* wrow = W + (j0 + jj) * HID;
#pragma unroll
            for (int k = 0; k < HID; ++k) acc[k] = fmaf(ev, wrow[k], acc[k]);
        }
    }
#pragma unroll
    for (int k = 0; k < HID; ++k) g[k] = fmaxf(acc[k], 0.f);
}

// o = g[32] @ P[32][32]   (P wave-uniform -> scalar loads)
__device__ __forceinline__ void proj32(const float* __restrict__ g,
                                       const float* __restrict__ P,
                                       float* __restrict__ o) {
    float acc[HID];
#pragma unroll
    for (int k = 0; k < HID; ++k) acc[k] = 0.f;
#pragma unroll 4
    for (int j = 0; j < HID; ++j) {
        float gv = g[j];
        const float* pr = P + j * HID;
#pragma unroll
        for (int k = 0; k < HID; ++k) acc[k] = fmaf(gv, pr[k], acc[k]);
    }
#pragma unroll
    for (int k = 0; k < HID; ++k) o[k] = acc[k];
}

__device__ __forceinline__ void store32(float* __restrict__ dst, const float* __restrict__ v) {
#pragma unroll
    for (int k = 0; k < HID; k += 4) {
        float4 t = {v[k], v[k + 1], v[k + 2], v[k + 3]};
        *(float4*)(dst + k) = t;
    }
}

// ---------------------------------------------------------------------------
// Per-node precompute: a0 = relu(e0@W0)@A, a1 = relu(e1@W1)@A,
//                      b1 = relu(e1@W1)@B, b2 = relu(e2@W2)@B
// where We1 = [A(32x32); B(32x32); T(32x32)] over the concat axis.
__global__ __launch_bounds__(256) void node_kernel(
    const float* __restrict__ emb0, const float* __restrict__ emb1,
    const float* __restrict__ emb2, const int* __restrict__ n_map,
    const float* __restrict__ W0, const float* __restrict__ W1,
    const float* __restrict__ W2, const float* __restrict__ We1,
    float* __restrict__ a0, float* __restrict__ a1,
    float* __restrict__ b1, float* __restrict__ b2, int n_nodes) {
    int n = blockIdx.x * blockDim.x + threadIdx.x;
    if (n >= n_nodes) return;
    int gn = n_map[n];
    const float* A = We1;             // rows 0..31
    const float* B = We1 + 32 * HID;  // rows 32..63

    float g[HID], o[HID];

    mlp_layer<128>(emb0 + (size_t)gn * 128, W0, g);
    proj32(g, A, o);
    store32(a0 + (size_t)n * HID, o);

    mlp_layer<256>(emb1 + (size_t)gn * 256, W1, g);
    proj32(g, A, o);
    store32(a1 + (size_t)n * HID, o);
    proj32(g, B, o);
    store32(b1 + (size_t)n * HID, o);

    mlp_layer<64>(emb2 + (size_t)gn * 64, W2, g);
    proj32(g, B, o);
    store32(b2 + (size_t)n * HID, o);
}

// t2[b] = relu(emb2[n_map[offset_node[b]]] @ W2) @ T
__global__ __launch_bounds__(256) void target_kernel(
    const float* __restrict__ emb2, const int* __restrict__ n_map,
    const int* __restrict__ offset_node, const float* __restrict__ W2,
    const float* __restrict__ We1, float* __restrict__ t2, int batch) {
    int b = blockIdx.x * blockDim.x + threadIdx.x;
    if (b >= batch) return;
    int gn = n_map[offset_node[b]];
    const float* T = We1 + 64 * HID;
    float g[HID], o[HID];
    mlp_layer<64>(emb2 + (size_t)gn * 64, W2, g);
    proj32(g, T, o);
    store32(t2 + (size_t)b * HID, o);
}

// ---------------------------------------------------------------------------
// Per-edge: att = relu(SA[src] + DB[dst] + t2[batch] + be1) @ We2 + be2
__global__ __launch_bounds__(256) void edge_kernel(
    const int* __restrict__ hop_idx, int n_e, const int* __restrict__ src,
    const int* __restrict__ dst, const int* __restrict__ e_batch,
    const float* __restrict__ SA, const float* __restrict__ DB,
    const float* __restrict__ t2, const float* __restrict__ be1,
    const float* __restrict__ We2, const float* __restrict__ be2,
    float* __restrict__ out) {
    int i = blockIdx.x * blockDim.x + threadIdx.x;
    if (i >= n_e) return;
    int e = hop_idx[i];
    const float* sv = SA + (size_t)src[e] * HID;
    const float* dv = DB + (size_t)dst[e] * HID;
    const float* tv = t2 + (size_t)e_batch[e] * HID;
    float att = be2[0];
#pragma unroll
    for (int k = 0; k < HID; k += 4) {
        float4 s4 = *(const float4*)(sv + k);
        float4 d4 = *(const float4*)(dv + k);
        float4 t4 = *(const float4*)(tv + k);
        float h;
        h = fmaxf(s4.x + d4.x + t4.x + be1[k + 0], 0.f); att = fmaf(h, We2[k + 0], att);
        h = fmaxf(s4.y + d4.y + t4.y + be1[k + 1], 0.f); att = fmaf(h, We2[k + 1], att);
        h = fmaxf(s4.z + d4.z + t4.z + be1[k + 2], 0.f); att = fmaf(h, We2[k + 2], att);
        h = fmaxf(s4.w + d4.w + t4.w + be1[k + 3], 0.f); att = fmaf(h, We2[k + 3], att);
    }
    out[e] = att;
}

// ---------------------------------------------------------------------------
extern "C" void kernel_launch(void* const* d_in, const int* in_sizes, int n_in,
                              void* d_out, int out_size, void* d_ws, size_t ws_size,
                              hipStream_t stream) {
    const float* emb0 = (const float*)d_in[0];
    const float* emb1 = (const float*)d_in[1];
    const float* emb2 = (const float*)d_in[2];
    const int* n_map = (const int*)d_in[3];
    const int* src = (const int*)d_in[4];
    const int* dst = (const int*)d_in[5];
    const int* e_batch = (const int*)d_in[6];
    const int* offset_node = (const int*)d_in[7];
    const int* one_hop = (const int*)d_in[8];
    const int* two_hop = (const int*)d_in[9];
    const float* W0 = (const float*)d_in[10];
    const float* W1 = (const float*)d_in[11];
    const float* W2 = (const float*)d_in[12];
    const float* We1 = (const float*)d_in[13];
    const float* be1 = (const float*)d_in[14];
    const float* We2 = (const float*)d_in[15];
    const float* be2 = (const float*)d_in[16];

    const int n_nodes = in_sizes[3];
    const int E = in_sizes[4];
    const int batch = in_sizes[7];
    const int H1 = in_sizes[8];  // one-hop edge count
    const int H2 = in_sizes[9];  // two-hop edge count

    float* out = (float*)d_out;

    // workspace layout: a0 | a1 | b1 | b2 | t2
    float* a0 = (float*)d_ws;
    float* a1 = a0 + (size_t)n_nodes * HID;
    float* b1 = a1 + (size_t)n_nodes * HID;
    float* b2 = b1 + (size_t)n_nodes * HID;
    float* t2 = b2 + (size_t)n_nodes * HID;

    // 1) fill output with MIN_WEIGHT
    {
        int total = 2 * E;
        int blocks = (total + 255) / 256;
        if (blocks > 2048) blocks = 2048;
        fill_kernel<<<blocks, 256, 0, stream>>>(out, total, MIN_WEIGHT);
    }
    // 2) per-node projected features
    node_kernel<<<(n_nodes + 255) / 256, 256, 0, stream>>>(
        emb0, emb1, emb2, n_map, W0, W1, W2, We1, a0, a1, b1, b2, n_nodes);
    // 3) per-batch target features
    target_kernel<<<(batch + 255) / 256, 256, 0, stream>>>(
        emb2, n_map, offset_node, W2, We1, t2, batch);
    // 4) one-hop edges -> slab 1 ; uses a1 (src via W1@A) + b2 (dst via W2@B)
    edge_kernel<<<(H1 + 255) / 256, 256, 0, stream>>>(
        one_hop, H1, src, dst, e_batch, a1, b2, t2, be1, We2, be2, out + (size_t)E);
    // 5) two-hop edges -> slab 0 ; uses a0 (src via W0@A) + b1 (dst via W1@B)
    edge_kernel<<<(H2 + 255) / 256, 256, 0, stream>>>(
        two_hop, H2, src, dst, e_batch, a0, b1, t2, be1, We2, be2, out);
}